// Round 12
// baseline (33.352 us; speedup 1.0000x reference)
//
#include <hip/hip_runtime.h>
#include <math.h>

#define BATCH 256
#define CIN   3
#define COUT  16
#define DI    16
#define HI    32
#define WI    32

typedef _Float16 f16;
typedef f16   f16x4 __attribute__((ext_vector_type(4)));
typedef f16   f16x8 __attribute__((ext_vector_type(8)));
typedef float f32x4 __attribute__((ext_vector_type(4)));

#define LOG2E 1.44269504088896340736f

// LDS slab (f16 units): xs[dd][hh][w][ci], ci stride 1 (3 cin + zero pad),
// w stride 4, row stride ROWU=144 f16 (288B), plane stride PLANEU=4320.
// 288B ≡ 32 mod 128 -> 16-col lane group covers all 32 banks; kq-group
// offsets {0,64,96,0} mod 128 -> <=2-way aliasing (free). [R5: 737K conflicts]
#define ROWU   144
#define PLANEU 4320
#define XS_N   (6 * PLANEU)              // 51840 B -> 3 WG/CU
#define G8OFF  (2 * PLANEU + 2 * ROWU)   // (kd=2,kh=2) row offset

#define SV8(a, b) __builtin_shufflevector(a, b, 0, 1, 2, 3, 4, 5, 6, 7)
#define MFMA16(A, B, C) __builtin_amdgcn_mfma_f32_16x16x32_f16(A, B, C, 0, 0, 0)

// VALU-pipe max-reduce over the 16-lane col group (DPP row_ror). Exact for max.
#define DPPMAX(v, ctrl) do {                                                  \
    int t_ = __builtin_amdgcn_update_dpp(                                     \
        0, __builtin_bit_cast(int, v), (ctrl), 0xF, 0xF, false);              \
    v = fmaxf(v, __builtin_bit_cast(float, t_));                              \
} while (0)

// ---------------------------------------------------------------------------
// Fused conv3d + bias + channel-softmax + 4^3 maxpool.
// One 640-thread WG (10 waves) per (b,pd); 768 WGs = 3 WG/CU = 30 waves/CU.
// ONE barrier; each wave owns ~5 complete pool cells. g8 B-reads predicated
// by kq (A=0 slots need no LDS read): 64 -> 54 B/lane per (cell,d), -16%
// on the LDS pipe, which R11 showed is the binding resource.
// ---------------------------------------------------------------------------
__global__ __launch_bounds__(640, 8) void conv_sm_pool_mfma(
    const float* __restrict__ x, const float* __restrict__ W,
    const float* __restrict__ bias, float* __restrict__ out)
{
    __shared__ __align__(16) f16 xs[XS_N];

    const int tid  = threadIdx.x;
    const int lane = tid & 63;
    const int wave = tid >> 6;           // 0..9
    const int b    = blockIdx.x / 3;
    const int pd   = blockIdx.x % 3;
    const int d0   = pd * 4;

    const int col = lane & 15;     // MFMA column = position in cell (hl*4+wl)
    const int kq  = lane >> 4;     // K-slot group

    // ---- W gather -> A-fragments, PRE-SCALED by log2e (exp -> exp2) ----
    // k = g*4 + ci, g = kd*3+kh; this lane holds groups 2kq, 2kq+1.
    const float* wc  = W + col * 81;
    const float* wqp = wc + kq * 6;
    f16x8 wm[3];
    #pragma unroll
    for (int kw = 0; kw < 3; ++kw) {
        #pragma unroll
        for (int j = 0; j < 8; ++j) {
            const int ci = j & 3, jj = j >> 2;
            float v = (ci < 3) ? wqp[ci * 27 + 3 * jj + kw] * LOG2E : 0.f;
            wm[kw][j] = (f16)v;
        }
    }
    f16x8 wg = {};
    if (kq == 0) {
        #pragma unroll
        for (int j = 0; j < 8; ++j) {
            const int ci = j & 3, kw = j >> 2;
            if (ci < 3) wg[j] = (f16)(wc[ci * 27 + 24 + kw] * LOG2E);
        }
    } else if (kq == 1) {
        #pragma unroll
        for (int j = 0; j < 3; ++j) wg[j] = (f16)(wc[j * 27 + 26] * LOG2E);
    }
    const float4 braw = *(const float4*)(bias + kq * 4);
    float4 bv;
    bv.x = braw.x * LOG2E; bv.y = braw.y * LOG2E;
    bv.z = braw.z * LOG2E; bv.w = braw.w * LOG2E;

    // ---- Stage x[b,:,d0..d0+5,0..29,0..31] -> cin-interleaved f16 LDS ----
    for (int i = tid; i < 1440; i += 640) {              // 6 dd * 30 hh * 8 wq
        int wqd = i & 7;
        int r   = i >> 3;
        int hh  = r % 30;
        int dd  = r / 30;
        const float* px = x + ((size_t)b * 48 + (d0 + dd)) * 1024 + hh * 32 + wqd * 4;
        float4 a0 = *(const float4*)(px);
        float4 a1 = *(const float4*)(px + 16384);
        float4 a2 = *(const float4*)(px + 32768);
        f16x8 p0, p1;
        p0[0] = (f16)a0.x; p0[1] = (f16)a1.x; p0[2] = (f16)a2.x; p0[3] = (f16)0.f;
        p0[4] = (f16)a0.y; p0[5] = (f16)a1.y; p0[6] = (f16)a2.y; p0[7] = (f16)0.f;
        p1[0] = (f16)a0.z; p1[1] = (f16)a1.z; p1[2] = (f16)a2.z; p1[3] = (f16)0.f;
        p1[4] = (f16)a0.w; p1[5] = (f16)a1.w; p1[6] = (f16)a2.w; p1[7] = (f16)0.f;
        f16* dst = xs + ((dd * 30 + hh) * 36 + wqd * 4) * 4;
        *(f16x8*)(dst)     = p0;
        *(f16x8*)(dst + 8) = p1;
    }

    // per-lane B-read invariants
    const int g0   = kq * 2;
    const int off1 = (g0 / 3) * PLANEU + (g0 % 3) * ROWU;
    const int off2 = ((g0 + 1) / 3) * PLANEU + ((g0 + 1) % 3) * ROWU;
    const int hl = col >> 2, wl = col & 3;
    const int spat  = hl * ROWU + wl * 4;

    __syncthreads();   // the only barrier

    for (int c = wave; c < 49; c += 10) {    // cell = ch*7 + pw, ~5 per wave
        const int ch = c / 7;
        const int pw = c - ch * 7;
        const f16* base = xs + ch * 4 * ROWU + pw * 16 + spat;
        const f16* a1 = base + off1;
        const f16* a2 = base + off2;
        const f16* a3 = base + G8OFF;

        f32x4 acc[4];
        #pragma unroll
        for (int d = 0; d < 4; ++d) {
            const int dp = d * PLANEU;
            // main B fragments: 6 b64, all slots feed nonzero A
            f16x4 b10 = *(const f16x4*)(a1 + dp);
            f16x4 b20 = *(const f16x4*)(a2 + dp);
            f16x4 b11 = *(const f16x4*)(a1 + dp + 4);
            f16x4 b21 = *(const f16x4*)(a2 + dp + 4);
            f16x4 b12 = *(const f16x4*)(a1 + dp + 8);
            f16x4 b22 = *(const f16x4*)(a2 + dp + 8);
            // g8 fragment: A nonzero only for K slots 0..11 ->
            // kq0: 2 reads, kq1: 1 read, kq2/3: none (B junk annihilated by A=0)
            f16x4 ga = b10, gb = b11;
            if (kq == 0) {
                ga = *(const f16x4*)(a3 + dp);
                gb = *(const f16x4*)(a3 + dp + 4);
            } else if (kq == 1) {
                ga = *(const f16x4*)(a3 + dp + 8);
            }

            __builtin_amdgcn_s_setprio(1);
            f32x4 a_ = {0.f, 0.f, 0.f, 0.f};
            a_ = MFMA16(wm[0], SV8(b10, b20), a_);
            a_ = MFMA16(wm[1], SV8(b11, b21), a_);
            a_ = MFMA16(wm[2], SV8(b12, b22), a_);
            a_ = MFMA16(wg,    SV8(ga,  gb),  a_);
            __builtin_amdgcn_s_setprio(0);
            acc[d] = a_;
        }

        // ---- batched softmax (exp2; weights prescaled) ----
        float ev[4][4], s[4];
        #pragma unroll
        for (int d = 0; d < 4; ++d) {
            float y0 = acc[d][0] + bv.x, y1 = acc[d][1] + bv.y;
            float y2 = acc[d][2] + bv.z, y3 = acc[d][3] + bv.w;
            ev[d][0] = __builtin_amdgcn_exp2f(y0);
            ev[d][1] = __builtin_amdgcn_exp2f(y1);
            ev[d][2] = __builtin_amdgcn_exp2f(y2);
            ev[d][3] = __builtin_amdgcn_exp2f(y3);
            s[d] = (ev[d][0] + ev[d][1]) + (ev[d][2] + ev[d][3]);
        }
        #pragma unroll
        for (int d = 0; d < 4; ++d) s[d] += __shfl_xor(s[d], 16);
        #pragma unroll
        for (int d = 0; d < 4; ++d) s[d] += __shfl_xor(s[d], 32);

        f32x4 pm = {0.f, 0.f, 0.f, 0.f};
        #pragma unroll
        for (int d = 0; d < 4; ++d) {
            float iv = __builtin_amdgcn_rcpf(s[d]);
            pm[0] = fmaxf(pm[0], ev[d][0] * iv);
            pm[1] = fmaxf(pm[1], ev[d][1] * iv);
            pm[2] = fmaxf(pm[2], ev[d][2] * iv);
            pm[3] = fmaxf(pm[3], ev[d][3] * iv);
        }

        // ---- pool over the 16 cell positions on the VALU pipe ----
        #pragma unroll
        for (int r = 0; r < 4; ++r) {
            float v = pm[r];
            DPPMAX(v, 0x128);   // row_ror:8
            DPPMAX(v, 0x124);   // row_ror:4
            DPPMAX(v, 0x122);   // row_ror:2
            DPPMAX(v, 0x121);   // row_ror:1
            pm[r] = v;
        }

        if (col == 0) {
            float* po = out + ((size_t)b * COUT + kq * 4) * 147 + pd * 49 + c;
            po[0]   = pm[0];
            po[147] = pm[1];
            po[294] = pm[2];
            po[441] = pm[3];
        }
    }
}

extern "C" void kernel_launch(void* const* d_in, const int* in_sizes, int n_in,
                              void* d_out, int out_size, void* d_ws, size_t ws_size,
                              hipStream_t stream) {
    const float* x    = (const float*)d_in[0];
    const float* W    = (const float*)d_in[1];
    const float* bias = (const float*)d_in[2];
    float* out = (float*)d_out;

    conv_sm_pool_mfma<<<BATCH * 3, 640, 0, stream>>>(x, W, bias, out);
}

// Round 13
// 32.806 us; speedup vs baseline: 1.0166x; 1.0166x over previous
//
#include <hip/hip_runtime.h>
#include <math.h>

#define BATCH 256
#define CIN   3
#define COUT  16
#define DI    16
#define HI    32
#define WI    32

typedef _Float16 f16;
typedef f16   f16x4 __attribute__((ext_vector_type(4)));
typedef f16   f16x8 __attribute__((ext_vector_type(8)));
typedef float f32x4 __attribute__((ext_vector_type(4)));

#define LOG2E 1.44269504088896340736f

// LDS slab (f16 units): xs[dd][hh_local][w][ci]; 18 h-rows per chunk (h-split),
// ci stride 1 (3 cin + zero pad), w stride 4, row stride ROWU=144 f16 (288B),
// plane stride PLANEU=18*144. 288B ≡ 32 mod 128 -> 16-col lane group covers
// all 32 banks; kq offsets {0,64,96,0} mod 128 -> <=2-way alias (free).
#define ROWU   144
#define PLANEU (18 * ROWU)               // 2592 f16
#define XS_N   (6 * PLANEU)              // 15552 f16 = 31104 B -> 4 WG/CU (wave-capped)
#define G8OFF  (2 * PLANEU + 2 * ROWU)   // (kd=2,kh=2) offset

#define SV8(a, b) __builtin_shufflevector(a, b, 0, 1, 2, 3, 4, 5, 6, 7)
#define MFMA16(A, B, C) __builtin_amdgcn_mfma_f32_16x16x32_f16(A, B, C, 0, 0, 0)

// VALU-pipe max-reduce over the 16-lane col group (DPP row_ror). Exact for max.
#define DPPMAX(v, ctrl) do {                                                  \
    int t_ = __builtin_amdgcn_update_dpp(                                     \
        0, __builtin_bit_cast(int, v), (ctrl), 0xF, 0xF, false);              \
    v = fmaxf(v, __builtin_bit_cast(float, t_));                              \
} while (0)

// ---------------------------------------------------------------------------
// Fused conv3d + bias + channel-softmax + 4^3 maxpool.
// Grid 1536: one 512-thread WG per (b, pd, h-chunk). Chunk0: pool-rows 0..3
// (x rows 0..17), chunk1: pool-rows 4..6 (x rows 16..29). Full cache-line
// rows per chunk -> only 2 halo rows of extra HBM fetch (vs R8 w-split's 2x).
// 31.1 KB LDS -> 4 WG/CU x 8 waves = 32 waves/CU static. Pair-to-XCD swizzle
// keeps both chunks of a (b,pd) on one XCD's L2 (R9-proven, FETCH ~26MB).
// R11's proven body: exp2-prescaled weights, DPP pool, clean per-d CELLD.
// ---------------------------------------------------------------------------
__global__ __launch_bounds__(512, 8) void conv_sm_pool_mfma(
    const float* __restrict__ x, const float* __restrict__ W,
    const float* __restrict__ bias, float* __restrict__ out)
{
    __shared__ __align__(16) f16 xs[XS_N];

    const int tid  = threadIdx.x;
    const int lane = tid & 63;
    const int wave = tid >> 6;           // 0..7

    // wgid = [p_hi][hc][p_lo(3)] : both chunks of pair p share an XCD (hw %8)
    const int wgid = blockIdx.x;
    const int hc = (wgid >> 3) & 1;
    const int p  = ((wgid >> 4) << 3) | (wgid & 7);   // 0..767 = (b,pd)
    const int b  = p / 3;
    const int pd = p % 3;
    const int d0 = pd * 4;
    const int row0  = hc ? 16 : 0;       // first x-row staged
    const int nrows = hc ? 14 : 18;      // rows staged

    const int col = lane & 15;     // MFMA column = position in cell (hl*4+wl)
    const int kq  = lane >> 4;     // K-slot group

    // ---- W gather -> A-fragments, PRE-SCALED by log2e (exp -> exp2) ----
    // k = g*4 + ci, g = kd*3+kh; this lane holds groups 2kq, 2kq+1.
    const float* wc  = W + col * 81;
    const float* wqp = wc + kq * 6;
    f16x8 wm[3];
    #pragma unroll
    for (int kw = 0; kw < 3; ++kw) {
        #pragma unroll
        for (int j = 0; j < 8; ++j) {
            const int ci = j & 3, jj = j >> 2;
            float v = (ci < 3) ? wqp[ci * 27 + 3 * jj + kw] * LOG2E : 0.f;
            wm[kw][j] = (f16)v;
        }
    }
    f16x8 wg = {};
    if (kq == 0) {
        #pragma unroll
        for (int j = 0; j < 8; ++j) {
            const int ci = j & 3, kw = j >> 2;
            if (ci < 3) wg[j] = (f16)(wc[ci * 27 + 24 + kw] * LOG2E);
        }
    } else if (kq == 1) {
        #pragma unroll
        for (int j = 0; j < 3; ++j) wg[j] = (f16)(wc[j * 27 + 26] * LOG2E);
    }
    const float4 braw = *(const float4*)(bias + kq * 4);
    float4 bv;
    bv.x = braw.x * LOG2E; bv.y = braw.y * LOG2E;
    bv.z = braw.z * LOG2E; bv.w = braw.w * LOG2E;

    // ---- Stage x[b,:,d0..d0+5,row0..row0+nrows-1,0..31] -> f16 LDS ----
    const int nitems = 6 * nrows * 8;                    // dd * rows * wq
    for (int i = tid; i < nitems; i += 512) {
        int wqd = i & 7;
        int r   = i >> 3;
        int hh  = r % nrows;                             // local row
        int dd  = r / nrows;
        const float* px = x + ((size_t)b * 48 + (d0 + dd)) * 1024
                            + (row0 + hh) * 32 + wqd * 4;
        float4 a0 = *(const float4*)(px);
        float4 a1 = *(const float4*)(px + 16384);
        float4 a2 = *(const float4*)(px + 32768);
        f16x8 p0, p1;
        p0[0] = (f16)a0.x; p0[1] = (f16)a1.x; p0[2] = (f16)a2.x; p0[3] = (f16)0.f;
        p0[4] = (f16)a0.y; p0[5] = (f16)a1.y; p0[6] = (f16)a2.y; p0[7] = (f16)0.f;
        p1[0] = (f16)a0.z; p1[1] = (f16)a1.z; p1[2] = (f16)a2.z; p1[3] = (f16)0.f;
        p1[4] = (f16)a0.w; p1[5] = (f16)a1.w; p1[6] = (f16)a2.w; p1[7] = (f16)0.f;
        f16* dst = xs + (dd * 18 + hh) * ROWU + wqd * 16;
        *(f16x8*)(dst)     = p0;
        *(f16x8*)(dst + 8) = p1;
    }

    // per-lane B-read invariants
    const int g0   = kq * 2;
    const int off1 = (g0 / 3) * PLANEU + (g0 % 3) * ROWU;
    const int off2 = ((g0 + 1) / 3) * PLANEU + ((g0 + 1) % 3) * ROWU;
    const int hl = col >> 2, wl = col & 3;
    const int spat  = hl * ROWU + wl * 4;
    const int g8sel = (kq == 0) ? 0 : 8;

    __syncthreads();   // the only barrier

    const int ncell = hc ? 21 : 28;      // local cells: (ch_local, pw)
    for (int c = wave; c < ncell; c += 8) {
        const int chl = c / 7;           // local pool-row 0..3 / 0..2
        const int pw  = c - chl * 7;
        const f16* base = xs + chl * 4 * ROWU + pw * 16 + spat;
        const f16* a1 = base + off1;
        const f16* a2 = base + off2;
        const f16* a3 = base + G8OFF + g8sel;

        f32x4 acc[4];
        #pragma unroll
        for (int d = 0; d < 4; ++d) {
            const int dp = d * PLANEU;
            f16x4 b10 = *(const f16x4*)(a1 + dp);
            f16x4 b20 = *(const f16x4*)(a2 + dp);
            f16x4 b11 = *(const f16x4*)(a1 + dp + 4);
            f16x4 b21 = *(const f16x4*)(a2 + dp + 4);
            f16x4 b12 = *(const f16x4*)(a1 + dp + 8);
            f16x4 b22 = *(const f16x4*)(a2 + dp + 8);
            f16x4 ga  = *(const f16x4*)(a3 + dp);
            f16x4 gb  = *(const f16x4*)(a3 + dp + 4);
            f32x4 a_ = {0.f, 0.f, 0.f, 0.f};
            a_ = MFMA16(wm[0], SV8(b10, b20), a_);
            a_ = MFMA16(wm[1], SV8(b11, b21), a_);
            a_ = MFMA16(wm[2], SV8(b12, b22), a_);
            a_ = MFMA16(wg,    SV8(ga,  gb),  a_);
            acc[d] = a_;
        }

        // ---- batched softmax (exp2; weights prescaled) ----
        float ev[4][4], s[4];
        #pragma unroll
        for (int d = 0; d < 4; ++d) {
            float y0 = acc[d][0] + bv.x, y1 = acc[d][1] + bv.y;
            float y2 = acc[d][2] + bv.z, y3 = acc[d][3] + bv.w;
            ev[d][0] = __builtin_amdgcn_exp2f(y0);
            ev[d][1] = __builtin_amdgcn_exp2f(y1);
            ev[d][2] = __builtin_amdgcn_exp2f(y2);
            ev[d][3] = __builtin_amdgcn_exp2f(y3);
            s[d] = (ev[d][0] + ev[d][1]) + (ev[d][2] + ev[d][3]);
        }
        #pragma unroll
        for (int d = 0; d < 4; ++d) s[d] += __shfl_xor(s[d], 16);
        #pragma unroll
        for (int d = 0; d < 4; ++d) s[d] += __shfl_xor(s[d], 32);

        f32x4 pm = {0.f, 0.f, 0.f, 0.f};
        #pragma unroll
        for (int d = 0; d < 4; ++d) {
            float iv = __builtin_amdgcn_rcpf(s[d]);
            pm[0] = fmaxf(pm[0], ev[d][0] * iv);
            pm[1] = fmaxf(pm[1], ev[d][1] * iv);
            pm[2] = fmaxf(pm[2], ev[d][2] * iv);
            pm[3] = fmaxf(pm[3], ev[d][3] * iv);
        }

        // ---- pool over the 16 cell positions on the VALU pipe ----
        #pragma unroll
        for (int r = 0; r < 4; ++r) {
            float v = pm[r];
            DPPMAX(v, 0x128);   // row_ror:8
            DPPMAX(v, 0x124);   // row_ror:4
            DPPMAX(v, 0x122);   // row_ror:2
            DPPMAX(v, 0x121);   // row_ror:1
            pm[r] = v;
        }

        if (col == 0) {
            const int ch = hc ? 4 + chl : chl;
            float* po = out + ((size_t)b * COUT + kq * 4) * 147 + pd * 49 + ch * 7 + pw;
            po[0]   = pm[0];
            po[147] = pm[1];
            po[294] = pm[2];
            po[441] = pm[3];
        }
    }
}

extern "C" void kernel_launch(void* const* d_in, const int* in_sizes, int n_in,
                              void* d_out, int out_size, void* d_ws, size_t ws_size,
                              hipStream_t stream) {
    const float* x    = (const float*)d_in[0];
    const float* W    = (const float*)d_in[1];
    const float* bias = (const float*)d_in[2];
    float* out = (float*)d_out;

    conv_sm_pool_mfma<<<BATCH * 3 * 2, 512, 0, stream>>>(x, W, bias, out);
}

// Round 14
// 32.798 us; speedup vs baseline: 1.0169x; 1.0002x over previous
//
#include <hip/hip_runtime.h>
#include <math.h>

#define BATCH 256
#define CIN   3
#define COUT  16
#define DI    16
#define HI    32
#define WI    32

typedef _Float16 f16;
typedef f16   f16x4 __attribute__((ext_vector_type(4)));
typedef f16   f16x8 __attribute__((ext_vector_type(8)));
typedef float f32x4 __attribute__((ext_vector_type(4)));

#define LOG2E 1.44269504088896340736f

// LDS slab (f16 units): xs[dd][hh_local][w][ci]; 18 h-rows per chunk (h-split),
// ci stride 1 (3 cin + pad), w stride 4, row stride ROWU=144 f16 (288B),
// plane stride PLANEU=18*144. 288B ≡ 32 mod 128 -> conflict-free B reads.
// PAD SLOTS HOLD 1.0 (not 0): every K-slot with ci==3 has A==0 in all MFMAs
// EXCEPT g8/kq0/j3, whose A = bias*log2e -> bias injected via matrix pipe.
#define ROWU   144
#define PLANEU (18 * ROWU)               // 2592 f16
#define XS_N   (6 * PLANEU)              // 31104 B -> 4 WG/CU (wave-capped)
#define G8OFF  (2 * PLANEU + 2 * ROWU)   // (kd=2,kh=2) offset

#define SV8(a, b) __builtin_shufflevector(a, b, 0, 1, 2, 3, 4, 5, 6, 7)
#define MFMA16(A, B, C) __builtin_amdgcn_mfma_f32_16x16x32_f16(A, B, C, 0, 0, 0)

// VALU-pipe max-reduce over the 16-lane col group (DPP row_ror). Exact for max.
#define DPPMAX(v, ctrl) do {                                                  \
    int t_ = __builtin_amdgcn_update_dpp(                                     \
        0, __builtin_bit_cast(int, v), (ctrl), 0xF, 0xF, false);              \
    v = fmaxf(v, __builtin_bit_cast(float, t_));                              \
} while (0)

// ---------------------------------------------------------------------------
// Fused conv3d + bias + channel-softmax + 4^3 maxpool.
// Grid 1536: one 512-thread WG per (b, pd, h-chunk); pair-to-XCD swizzle.
// 31.1 KB LDS + <=64-reg fused body -> 4 WG/CU x 8 waves = 32 waves/CU.
// Per d: 8 ds_read_b64 -> 4 MFMAs (bias folded in) -> exp2 softmax -> pm.
// ---------------------------------------------------------------------------
__global__ __launch_bounds__(512, 8) void conv_sm_pool_mfma(
    const float* __restrict__ x, const float* __restrict__ W,
    const float* __restrict__ bias, float* __restrict__ out)
{
    __shared__ __align__(16) f16 xs[XS_N];

    const int tid  = threadIdx.x;
    const int lane = tid & 63;
    const int wave = tid >> 6;           // 0..7

    // wgid = [p_hi][hc][p_lo(3)] : both chunks of pair p share an XCD (hw %8)
    const int wgid = blockIdx.x;
    const int hc = (wgid >> 3) & 1;
    const int p  = ((wgid >> 4) << 3) | (wgid & 7);   // 0..767 = (b,pd)
    const int b  = p / 3;
    const int pd = p % 3;
    const int d0 = pd * 4;
    const int row0  = hc ? 16 : 0;       // first x-row staged
    const int nrows = hc ? 14 : 18;      // rows staged

    const int col = lane & 15;     // MFMA column = position in cell (hl*4+wl)
    const int kq  = lane >> 4;     // K-slot group

    // ---- W gather -> A-fragments, PRE-SCALED by log2e (exp -> exp2) ----
    // k = g*4 + ci, g = kd*3+kh; this lane holds groups 2kq, 2kq+1.
    const float* wc  = W + col * 81;
    const float* wqp = wc + kq * 6;
    f16x8 wm[3];
    #pragma unroll
    for (int kw = 0; kw < 3; ++kw) {
        #pragma unroll
        for (int j = 0; j < 8; ++j) {
            const int ci = j & 3, jj = j >> 2;
            float v = (ci < 3) ? wqp[ci * 27 + 3 * jj + kw] * LOG2E : 0.f;
            wm[kw][j] = (f16)v;
        }
    }
    f16x8 wg = {};
    if (kq == 0) {
        #pragma unroll
        for (int j = 0; j < 8; ++j) {
            const int ci = j & 3, kw = j >> 2;
            if (ci < 3) wg[j] = (f16)(wc[ci * 27 + 24 + kw] * LOG2E);
        }
        // bias slot: k=3 is the (kd2,kh2) row's ci-pad, staged as B=1.0
        wg[3] = (f16)(bias[col] * LOG2E);
    } else if (kq == 1) {
        #pragma unroll
        for (int j = 0; j < 3; ++j) wg[j] = (f16)(wc[j * 27 + 26] * LOG2E);
    }

    // ---- Stage x[b,:,d0..d0+5,row0..,0..31] -> f16 LDS; ci-pad = 1.0 ----
    const int nitems = 6 * nrows * 8;                    // dd * rows * wq
    for (int i = tid; i < nitems; i += 512) {
        int wqd = i & 7;
        int r   = i >> 3;
        int hh  = r % nrows;                             // local row
        int dd  = r / nrows;
        const float* px = x + ((size_t)b * 48 + (d0 + dd)) * 1024
                            + (row0 + hh) * 32 + wqd * 4;
        float4 a0 = *(const float4*)(px);
        float4 a1 = *(const float4*)(px + 16384);
        float4 a2 = *(const float4*)(px + 32768);
        f16x8 p0, p1;
        p0[0] = (f16)a0.x; p0[1] = (f16)a1.x; p0[2] = (f16)a2.x; p0[3] = (f16)1.f;
        p0[4] = (f16)a0.y; p0[5] = (f16)a1.y; p0[6] = (f16)a2.y; p0[7] = (f16)1.f;
        p1[0] = (f16)a0.z; p1[1] = (f16)a1.z; p1[2] = (f16)a2.z; p1[3] = (f16)1.f;
        p1[4] = (f16)a0.w; p1[5] = (f16)a1.w; p1[6] = (f16)a2.w; p1[7] = (f16)1.f;
        f16* dst = xs + (dd * 18 + hh) * ROWU + wqd * 16;
        *(f16x8*)(dst)     = p0;
        *(f16x8*)(dst + 8) = p1;
    }

    // per-lane B-read invariants
    const int g0   = kq * 2;
    const int off1 = (g0 / 3) * PLANEU + (g0 % 3) * ROWU;
    const int off2 = ((g0 + 1) / 3) * PLANEU + ((g0 + 1) % 3) * ROWU;
    const int hl = col >> 2, wl = col & 3;
    const int spat  = hl * ROWU + wl * 4;
    const int g8sel = (kq == 0) ? 0 : 8;

    __syncthreads();   // the only barrier

    const int ncell = hc ? 21 : 28;      // local cells: (ch_local, pw)
    for (int c = wave; c < ncell; c += 8) {
        const int chl = c / 7;           // local pool-row
        const int pw  = c - chl * 7;
        const f16* base = xs + chl * 4 * ROWU + pw * 16 + spat;
        const f16* a1 = base + off1;
        const f16* a2 = base + off2;
        const f16* a3 = base + G8OFF + g8sel;

        f32x4 pm = {0.f, 0.f, 0.f, 0.f};

        #pragma unroll
        for (int d = 0; d < 4; ++d) {
            const int dp = d * PLANEU;
            f16x4 b10 = *(const f16x4*)(a1 + dp);
            f16x4 b20 = *(const f16x4*)(a2 + dp);
            f16x4 b11 = *(const f16x4*)(a1 + dp + 4);
            f16x4 b21 = *(const f16x4*)(a2 + dp + 4);
            f16x4 b12 = *(const f16x4*)(a1 + dp + 8);
            f16x4 b22 = *(const f16x4*)(a2 + dp + 8);
            f16x4 ga  = *(const f16x4*)(a3 + dp);
            f16x4 gb  = *(const f16x4*)(a3 + dp + 4);

            f32x4 a_ = {0.f, 0.f, 0.f, 0.f};
            a_ = MFMA16(wm[0], SV8(b10, b20), a_);
            a_ = MFMA16(wm[1], SV8(b11, b21), a_);
            a_ = MFMA16(wm[2], SV8(b12, b22), a_);
            a_ = MFMA16(wg,    SV8(ga,  gb),  a_);   // includes +bias via k=3

            // softmax over 16 couts (exp2-domain), fold into pool max
            float e0 = __builtin_amdgcn_exp2f(a_[0]);
            float e1 = __builtin_amdgcn_exp2f(a_[1]);
            float e2 = __builtin_amdgcn_exp2f(a_[2]);
            float e3 = __builtin_amdgcn_exp2f(a_[3]);
            float s = (e0 + e1) + (e2 + e3);
            s += __shfl_xor(s, 16);
            s += __shfl_xor(s, 32);
            float iv = __builtin_amdgcn_rcpf(s);
            pm[0] = fmaxf(pm[0], e0 * iv);
            pm[1] = fmaxf(pm[1], e1 * iv);
            pm[2] = fmaxf(pm[2], e2 * iv);
            pm[3] = fmaxf(pm[3], e3 * iv);
        }

        // ---- pool over the 16 cell positions on the VALU pipe ----
        #pragma unroll
        for (int r = 0; r < 4; ++r) {
            float v = pm[r];
            DPPMAX(v, 0x128);   // row_ror:8
            DPPMAX(v, 0x124);   // row_ror:4
            DPPMAX(v, 0x122);   // row_ror:2
            DPPMAX(v, 0x121);   // row_ror:1
            pm[r] = v;
        }

        if (col == 0) {
            const int ch = hc ? 4 + chl : chl;
            float* po = out + ((size_t)b * COUT + kq * 4) * 147 + pd * 49 + ch * 7 + pw;
            po[0]   = pm[0];
            po[147] = pm[1];
            po[294] = pm[2];
            po[441] = pm[3];
        }
    }
}

extern "C" void kernel_launch(void* const* d_in, const int* in_sizes, int n_in,
                              void* d_out, int out_size, void* d_ws, size_t ws_size,
                              hipStream_t stream) {
    const float* x    = (const float*)d_in[0];
    const float* W    = (const float*)d_in[1];
    const float* bias = (const float*)d_in[2];
    float* out = (float*)d_out;

    conv_sm_pool_mfma<<<BATCH * 3 * 2, 512, 0, stream>>>(x, W, bias, out);
}

// Round 15
// 29.777 us; speedup vs baseline: 1.1200x; 1.1014x over previous
//
#include <hip/hip_runtime.h>
#include <math.h>

#define BATCH 256
#define CIN   3
#define COUT  16
#define DI    16
#define HI    32
#define WI    32

typedef _Float16 f16;
typedef f16   f16x4 __attribute__((ext_vector_type(4)));
typedef f16   f16x8 __attribute__((ext_vector_type(8)));
typedef float f32x4 __attribute__((ext_vector_type(4)));

#define LOG2E 1.44269504088896340736f

// LDS slab (f16 units): xs[dd][hh][w][ci], ci stride 1 (3 cin + pad),
// w stride 4, row stride ROWU=144 f16 (288B), plane stride PLANEU=4320.
// 288B ≡ 32 mod 128 -> conflict-free B reads (R5/R11: ~700K conflicts).
// PAD SLOTS HOLD 1.0: every ci-pad K-slot has A==0 in all MFMAs EXCEPT
// g8/kq0/j3, whose A = bias*log2e -> bias injected via the matrix pipe.
#define ROWU   144
#define PLANEU 4320
#define XS_N   (6 * PLANEU)              // 51840 B -> 3 WG/CU (24 waves/CU @512thr)
#define G8OFF  (2 * PLANEU + 2 * ROWU)   // (kd=2,kh=2) row offset

#define SV8(a, b) __builtin_shufflevector(a, b, 0, 1, 2, 3, 4, 5, 6, 7)
#define MFMA16(A, B, C) __builtin_amdgcn_mfma_f32_16x16x32_f16(A, B, C, 0, 0, 0)

// VALU-pipe max-reduce over the 16-lane col group (DPP row_ror). Exact for max.
#define DPPMAX(v, ctrl) do {                                                  \
    int t_ = __builtin_amdgcn_update_dpp(                                     \
        0, __builtin_bit_cast(int, v), (ctrl), 0xF, 0xF, false);              \
    v = fmaxf(v, __builtin_bit_cast(float, t_));                              \
} while (0)

// 8 ds_read_b64 into NAMED set P0..P7 (rule #20: static names, no arrays)
#define LOADS(P, dp)                                                          \
    P##0 = *(const f16x4*)(a1 + (dp));                                        \
    P##1 = *(const f16x4*)(a2 + (dp));                                        \
    P##2 = *(const f16x4*)(a1 + (dp) + 4);                                    \
    P##3 = *(const f16x4*)(a2 + (dp) + 4);                                    \
    P##4 = *(const f16x4*)(a1 + (dp) + 8);                                    \
    P##5 = *(const f16x4*)(a2 + (dp) + 8);                                    \
    P##6 = *(const f16x4*)(a3 + (dp));                                        \
    P##7 = *(const f16x4*)(a3 + (dp) + 4);

// 4-chain MFMA (bias folded via g8 k=3) + exp2 softmax + pool-max fold
#define COMPUTE(P)  do {                                                      \
    f32x4 a_ = {0.f, 0.f, 0.f, 0.f};                                          \
    a_ = MFMA16(wm[0], SV8(P##0, P##1), a_);                                  \
    a_ = MFMA16(wm[1], SV8(P##2, P##3), a_);                                  \
    a_ = MFMA16(wm[2], SV8(P##4, P##5), a_);                                  \
    a_ = MFMA16(wg,    SV8(P##6, P##7), a_);                                  \
    float e0 = __builtin_amdgcn_exp2f(a_[0]);                                 \
    float e1 = __builtin_amdgcn_exp2f(a_[1]);                                 \
    float e2 = __builtin_amdgcn_exp2f(a_[2]);                                 \
    float e3 = __builtin_amdgcn_exp2f(a_[3]);                                 \
    float s_ = (e0 + e1) + (e2 + e3);                                         \
    s_ += __shfl_xor(s_, 16);                                                 \
    s_ += __shfl_xor(s_, 32);                                                 \
    float iv = __builtin_amdgcn_rcpf(s_);                                     \
    pm[0] = fmaxf(pm[0], e0 * iv);                                            \
    pm[1] = fmaxf(pm[1], e1 * iv);                                            \
    pm[2] = fmaxf(pm[2], e2 * iv);                                            \
    pm[3] = fmaxf(pm[3], e3 * iv);                                            \
} while (0)

// ---------------------------------------------------------------------------
// Fused conv3d + bias + channel-softmax + 4^3 maxpool.
// One 512-thread WG per (b,pd); 768 WGs = 3 WG/CU = 24 waves/CU, ONE barrier.
// Per cell: 2-stage software pipeline over d with NAMED A/B fragment sets --
// each 8-load block has a full compute block (~150-200cy MFMA+VALU) issued
// between load and use, hiding ds_read latency without array-indexed state
// (R7/R9 failure mode) or global-load register bloat (R6 failure mode).
// ---------------------------------------------------------------------------
__global__ __launch_bounds__(512, 6) void conv_sm_pool_mfma(
    const float* __restrict__ x, const float* __restrict__ W,
    const float* __restrict__ bias, float* __restrict__ out)
{
    __shared__ __align__(16) f16 xs[XS_N];

    const int tid  = threadIdx.x;
    const int lane = tid & 63;
    const int wave = tid >> 6;           // 0..7
    const int b    = blockIdx.x / 3;
    const int pd   = blockIdx.x % 3;
    const int d0   = pd * 4;

    const int col = lane & 15;     // MFMA column = position in cell (hl*4+wl)
    const int kq  = lane >> 4;     // K-slot group

    // ---- W gather -> A-fragments, PRE-SCALED by log2e (exp -> exp2) ----
    const float* wc  = W + col * 81;
    const float* wqp = wc + kq * 6;
    f16x8 wm[3];
    #pragma unroll
    for (int kw = 0; kw < 3; ++kw) {
        #pragma unroll
        for (int j = 0; j < 8; ++j) {
            const int ci = j & 3, jj = j >> 2;
            float v = (ci < 3) ? wqp[ci * 27 + 3 * jj + kw] * LOG2E : 0.f;
            wm[kw][j] = (f16)v;
        }
    }
    f16x8 wg = {};
    if (kq == 0) {
        #pragma unroll
        for (int j = 0; j < 8; ++j) {
            const int ci = j & 3, kw = j >> 2;
            if (ci < 3) wg[j] = (f16)(wc[ci * 27 + 24 + kw] * LOG2E);
        }
        wg[3] = (f16)(bias[col] * LOG2E);   // bias slot (B staged as 1.0)
    } else if (kq == 1) {
        #pragma unroll
        for (int j = 0; j < 3; ++j) wg[j] = (f16)(wc[j * 27 + 26] * LOG2E);
    }

    // ---- Stage x[b,:,d0..d0+5,0..29,0..31] -> f16 LDS; ci-pad = 1.0 ----
    for (int i = tid; i < 1440; i += 512) {              // 6 dd * 30 hh * 8 wq
        int wqd = i & 7;
        int r   = i >> 3;
        int hh  = r % 30;
        int dd  = r / 30;
        const float* px = x + ((size_t)b * 48 + (d0 + dd)) * 1024 + hh * 32 + wqd * 4;
        float4 v0 = *(const float4*)(px);
        float4 v1 = *(const float4*)(px + 16384);
        float4 v2 = *(const float4*)(px + 32768);
        f16x8 p0, p1;
        p0[0] = (f16)v0.x; p0[1] = (f16)v1.x; p0[2] = (f16)v2.x; p0[3] = (f16)1.f;
        p0[4] = (f16)v0.y; p0[5] = (f16)v1.y; p0[6] = (f16)v2.y; p0[7] = (f16)1.f;
        p1[0] = (f16)v0.z; p1[1] = (f16)v1.z; p1[2] = (f16)v2.z; p1[3] = (f16)1.f;
        p1[4] = (f16)v0.w; p1[5] = (f16)v1.w; p1[6] = (f16)v2.w; p1[7] = (f16)1.f;
        f16* dst = xs + ((dd * 30 + hh) * 36 + wqd * 4) * 4;
        *(f16x8*)(dst)     = p0;
        *(f16x8*)(dst + 8) = p1;
    }

    // per-lane B-read invariants
    const int g0   = kq * 2;
    const int off1 = (g0 / 3) * PLANEU + (g0 % 3) * ROWU;
    const int off2 = ((g0 + 1) / 3) * PLANEU + ((g0 + 1) % 3) * ROWU;
    const int hl = col >> 2, wl = col & 3;
    const int spat  = hl * ROWU + wl * 4;
    const int g8sel = (kq == 0) ? 0 : 8;

    __syncthreads();   // the only barrier

    for (int c = wave; c < 49; c += 8) {    // cell = ch*7 + pw, ~6 per wave
        const int ch = c / 7;
        const int pw = c - ch * 7;
        const f16* base = xs + ch * 4 * ROWU + pw * 16 + spat;
        const f16* a1 = base + off1;
        const f16* a2 = base + off2;
        const f16* a3 = base + G8OFF + g8sel;

        f32x4 pm = {0.f, 0.f, 0.f, 0.f};

        // named 2-stage pipeline over the 4 d-slices:
        // LA(0) LB(1) CA LA(2) CB LB(3) CA CB
        f16x4 A0, A1, A2, A3, A4, A5, A6, A7;
        f16x4 B0, B1, B2, B3, B4, B5, B6, B7;
        LOADS(A, 0)
        LOADS(B, PLANEU)
        COMPUTE(A);                 // d=0 (B's d=1 loads in flight)
        LOADS(A, 2 * PLANEU)
        COMPUTE(B);                 // d=1 (A's d=2 loads in flight)
        LOADS(B, 3 * PLANEU)
        COMPUTE(A);                 // d=2 (B's d=3 loads in flight)
        COMPUTE(B);                 // d=3

        // ---- pool over the 16 cell positions on the VALU pipe ----
        #pragma unroll
        for (int r = 0; r < 4; ++r) {
            float v = pm[r];
            DPPMAX(v, 0x128);   // row_ror:8
            DPPMAX(v, 0x124);   // row_ror:4
            DPPMAX(v, 0x122);   // row_ror:2
            DPPMAX(v, 0x121);   // row_ror:1
            pm[r] = v;
        }

        if (col == 0) {
            float* po = out + ((size_t)b * COUT + kq * 4) * 147 + pd * 49 + c;
            po[0]   = pm[0];
            po[147] = pm[1];
            po[294] = pm[2];
            po[441] = pm[3];
        }
    }
}

extern "C" void kernel_launch(void* const* d_in, const int* in_sizes, int n_in,
                              void* d_out, int out_size, void* d_ws, size_t ws_size,
                              hipStream_t stream) {
    const float* x    = (const float*)d_in[0];
    const float* W    = (const float*)d_in[1];
    const float* bias = (const float*)d_in[2];
    float* out = (float*)d_out;

    conv_sm_pool_mfma<<<BATCH * 3, 512, 0, stream>>>(x, W, bias, out);
}